// Round 9
// baseline (179.014 us; speedup 1.0000x reference)
//
#include <hip/hip_runtime.h>

#define Bn 4
#define Hn 512
#define Wn 512
#define HWn (Hn * Wn)

constexpr float kEps = 1e-5f;

// ws layout (floats) — every slot written before read, NO init required:
// [0..1023]     per-block gray maxes: batch b, block x -> ws[b*256 + x]
// [1024..1535]  per-main-block S1 partials (512 blocks)
// [1536..2047]  per-main-block S2 partials

__global__ __launch_bounds__(256) void gmax_kernel(
    const float* __restrict__ gray, float* __restrict__ gpart) {
  const int b = blockIdx.y;
  const int i = (blockIdx.x * 256 + threadIdx.x) << 2;
  const float4 g4 = *(const float4*)(gray + b * HWn + i);
  float lmax = fmaxf(fmaxf(g4.x, g4.y), fmaxf(g4.z, g4.w));
#pragma unroll
  for (int off = 32; off > 0; off >>= 1)
    lmax = fmaxf(lmax, __shfl_down(lmax, off));
  __shared__ float smax[4];
  const int lane = threadIdx.x & 63, wid = threadIdx.x >> 6;
  if (lane == 0) smax[wid] = lmax;
  __syncthreads();
  if (threadIdx.x == 0) {
    gpart[b * 256 + blockIdx.x] =
        fmaxf(fmaxf(smax[0], smax[1]), fmaxf(smax[2], smax[3]));
  }
}

// Block = 512 threads, 4 image rows (2048 px, 4 px/thread).
// fake/gamma/hdr^e staged in ZERO-PADDED LDS (stride 520, 4 pad cols each
// side, OOB rows zeroed) -> consume loop has no mask math at all.
// Tap-row order rotated per wave (rot = wave%5) to de-synchronize the
// post-barrier load convoy. Depth-1 rw prefetch (depth-2 spilled in r6;
// device-fence fused epilogue cost ~15us in r6/r7 — both reverted).
__global__ __launch_bounds__(512, 4) void main_kernel(
    const float* __restrict__ fake, const float* __restrict__ gamma,
    const float* __restrict__ hdr, const float* __restrict__ rw,
    const float* __restrict__ ff, const float* __restrict__ gpart,
    float* __restrict__ s1part, float* __restrict__ s2part) {
  __shared__ float smem[3][8][520];  // 49,920 B
  __shared__ float sh1[8], sh2[8], sh_gm[4];

  const int b = blockIdx.x >> 7;           // 128 blocks per batch
  const int h0 = (blockIdx.x & 127) << 2;  // first of 4 rows
  const float e = 1.0f - ff[b];

  const float* fb = fake + (size_t)b * HWn;
  const float* gb = gamma + (size_t)b * HWn;
  const float* hb = hdr + (size_t)b * HWn;

  const int t = threadIdx.x;
  const int lr = t >> 7;          // local row 0..3
  const int w0 = (t & 127) << 2;  // col base, multiple of 4
  const int h = h0 + lr;
  const float* rwb = rw + (size_t)b * 25 * HWn + (h << 9) + w0;
  const int rot = (t >> 6) % 5;   // wave-uniform tap-row rotation

  // Prefetch this wave's first tap-row BEFORE the staging barrier (loads
  // stay in flight across __syncthreads; only the waitcnt lands after).
  float4 wv[5];
#pragma unroll
  for (int d = 0; d < 5; ++d)
    wv[d] = *(const float4*)(rwb + (size_t)(rot * 5 + d) * HWn);

  // Batch gray-max: reduce this batch's 256 per-block partials (waves 0-3).
  if (t < 256) {
    float gm = gpart[(b << 8) + t];
#pragma unroll
    for (int off = 32; off > 0; off >>= 1)
      gm = fmaxf(gm, __shfl_down(gm, off));
    if ((t & 63) == 0) sh_gm[t >> 6] = gm;
  }

  // ---- staging: 3 arrays x 8 rows x 130 float4 (zero-padded) = 3120 ----
  // LDS float idx (c+4) holds img col c; idx 0..3 and 516..519 are zero;
  // OOB rows fully zero.
#pragma unroll
  for (int k = 0; k < 7; ++k) {
    const int i = t + (k << 9);
    if (i < 3120) {
      const int a = i / 1040;
      const int rem = i - a * 1040;
      const int r = rem / 130;
      const int j = rem - r * 130;  // float4 idx within padded row, 0..129
      const int grow = h0 - 2 + r;
      const bool ok =
          ((unsigned)grow < (unsigned)Hn) && (j >= 1) && (j <= 128);
      const int gr = min(max(grow, 0), Hn - 1);
      const int gc = min(max(j - 1, 0), 127) << 2;
      const float* src = (a == 0) ? fb : (a == 1) ? gb : hb;
      float4 v = *(const float4*)(src + (gr << 9) + gc);
      if (a == 2) {
        v.x = __powf(v.x, e);
        v.y = __powf(v.y, e);
        v.z = __powf(v.z, e);
        v.w = __powf(v.w, e);
      }
      if (!ok) v = make_float4(0.f, 0.f, 0.f, 0.f);
      *(float4*)&smem[a][r][j << 2] = v;
    }
  }
  __syncthreads();

  float Sw[4] = {0, 0, 0, 0}, Sf[4] = {0, 0, 0, 0}, Sf2[4] = {0, 0, 0, 0};
  float Sg[4] = {0, 0, 0, 0}, Sg2[4] = {0, 0, 0, 0}, Sh[4] = {0, 0, 0, 0};

#pragma unroll
  for (int s = 0; s < 5; ++s) {
    int dyi = rot + s;
    if (dyi >= 5) dyi -= 5;
    const int r = lr + dyi;  // staged row 0..7

    // current tap-row's weights; immediately start next tap-row's loads
    float4 wc[5];
#pragma unroll
    for (int d = 0; d < 5; ++d) wc[d] = wv[d];
    if (s < 4) {
      int dn = dyi + 1;
      if (dn >= 5) dn -= 5;
#pragma unroll
      for (int d = 0; d < 5; ++d)
        wv[d] = *(const float4*)(rwb + (size_t)(dn * 5 + d) * HWn);
    }

    // Window covers img cols w0-2 .. w0+5 -> LDS float idx w0+2 .. w0+9.
    // Read LDS idx w0 .. w0+11 as three aligned float4s; no masks needed.
    const float4 f0 = *(const float4*)&smem[0][r][w0];
    const float4 f1 = *(const float4*)&smem[0][r][w0 + 4];
    const float4 f2 = *(const float4*)&smem[0][r][w0 + 8];
    const float4 g0 = *(const float4*)&smem[1][r][w0];
    const float4 g1 = *(const float4*)&smem[1][r][w0 + 4];
    const float4 g2 = *(const float4*)&smem[1][r][w0 + 8];
    const float4 p0 = *(const float4*)&smem[2][r][w0];
    const float4 p1 = *(const float4*)&smem[2][r][w0 + 4];
    const float4 p2 = *(const float4*)&smem[2][r][w0 + 8];

    const float xf[12] = {f0.x, f0.y, f0.z, f0.w, f1.x, f1.y, f1.z, f1.w,
                          f2.x, f2.y, f2.z, f2.w};
    const float xg[12] = {g0.x, g0.y, g0.z, g0.w, g1.x, g1.y, g1.z, g1.w,
                          g2.x, g2.y, g2.z, g2.w};
    const float xh[12] = {p0.x, p0.y, p0.z, p0.w, p1.x, p1.y, p1.z, p1.w,
                          p2.x, p2.y, p2.z, p2.w};
#pragma unroll
    for (int dxi = 0; dxi < 5; ++dxi) {
      const float wk[4] = {wc[dxi].x, wc[dxi].y, wc[dxi].z, wc[dxi].w};
#pragma unroll
      for (int j = 0; j < 4; ++j) {
        const float w = wk[j];
        const float f = xf[j + dxi + 2], g = xg[j + dxi + 2],
                    hp = xh[j + dxi + 2];
        Sw[j] += w;
        const float wf = w * f;
        Sf[j] += wf;
        Sf2[j] = fmaf(wf, f, Sf2[j]);
        const float wg = w * g;
        Sg[j] += wg;
        Sg2[j] = fmaf(wg, g, Sg2[j]);
        Sh[j] = fmaf(w, hp, Sh[j]);
      }
    }
  }

  const float ffb = ff[b];
  const float gmax =
      fmaxf(fmaxf(sh_gm[0], sh_gm[1]), fmaxf(sh_gm[2], sh_gm[3]));
  float s1 = 0.0f, s2 = 0.0f;
#pragma unroll
  for (int j = 0; j < 4; ++j) {
    const float invSw = 1.0f / Sw[j];
    const float muf = Sf[j] * invSw;
    const float varf = fmaxf(Sf2[j] * invSw - muf * muf, 0.0f);
    const float stdf = sqrtf(varf + kEps);
    const float mug = Sg[j] * invSw;
    const float varg = fmaxf(Sg2[j] * invSw - mug * mug, 0.0f);
    const float stdg = sqrtf(varg + kEps);
    const float hpmu = Sh[j] * invSw;
    const float stdobj = (1.0f / ffb) * stdg * (hpmu + kEps) * gmax;
    const float r = 1.0f - stdf / (stdf + stdobj);
    const float wblf = Sw[j] - 1.0f;
    s1 = fmaf(r, wblf, s1);
    s2 += wblf;
  }
#pragma unroll
  for (int off = 32; off > 0; off >>= 1) {
    s1 += __shfl_down(s1, off);
    s2 += __shfl_down(s2, off);
  }
  const int lane = t & 63, wid = t >> 6;
  if (lane == 0) {
    sh1[wid] = s1;
    sh2[wid] = s2;
  }
  __syncthreads();
  if (t == 0) {
    float a1 = 0.0f, a2 = 0.0f;
#pragma unroll
    for (int i = 0; i < 8; ++i) {
      a1 += sh1[i];
      a2 += sh2[i];
    }
    s1part[blockIdx.x] = a1;
    s2part[blockIdx.x] = a2;
  }
}

__global__ __launch_bounds__(512) void final_kernel(
    const float* __restrict__ s1part, const float* __restrict__ s2part,
    float* __restrict__ out) {
  const int t = threadIdx.x;
  float s1 = s1part[t];
  float s2 = s2part[t];
#pragma unroll
  for (int off = 32; off > 0; off >>= 1) {
    s1 += __shfl_down(s1, off);
    s2 += __shfl_down(s2, off);
  }
  __shared__ float sh1[8], sh2[8];
  const int lane = t & 63, wid = t >> 6;
  if (lane == 0) {
    sh1[wid] = s1;
    sh2[wid] = s2;
  }
  __syncthreads();
  if (t == 0) {
    float a1 = 0.0f, a2 = 0.0f;
#pragma unroll
    for (int i = 0; i < 8; ++i) {
      a1 += sh1[i];
      a2 += sh2[i];
    }
    out[0] = a1 / a2;
  }
}

extern "C" void kernel_launch(void* const* d_in, const int* in_sizes, int n_in,
                              void* d_out, int out_size, void* d_ws,
                              size_t ws_size, hipStream_t stream) {
  const float* fake = (const float*)d_in[0];
  const float* gamma = (const float*)d_in[1];
  const float* hdr = (const float*)d_in[2];
  const float* rw = (const float*)d_in[3];
  const float* ff = (const float*)d_in[4];
  const float* gray = (const float*)d_in[5];
  float* out = (float*)d_out;
  float* ws = (float*)d_ws;
  float* gpart = ws;          // 1024 slots
  float* s1part = ws + 1024;  // 512 slots
  float* s2part = ws + 1536;  // 512 slots

  gmax_kernel<<<dim3(256, Bn), 256, 0, stream>>>(gray, gpart);
  main_kernel<<<Bn * Hn / 4, 512, 0, stream>>>(fake, gamma, hdr, rw, ff, gpart,
                                               s1part, s2part);
  final_kernel<<<1, 512, 0, stream>>>(s1part, s2part, out);
}

// Round 10
// 172.230 us; speedup vs baseline: 1.0394x; 1.0394x over previous
//
#include <hip/hip_runtime.h>

#define Bn 4
#define Hn 512
#define Wn 512
#define HWn (Hn * Wn)

constexpr float kEps = 1e-5f;

typedef float f4v __attribute__((ext_vector_type(4)));

// Non-temporal float4 load: every global byte in this problem is read
// exactly once -> bypass L1 line allocation (nt) to relieve the per-CU
// miss-queue (theory: L1 miss-service serialization is the ~50us wall).
__device__ __forceinline__ float4 nt_load4(const float* p) {
  f4v v = __builtin_nontemporal_load((const f4v*)p);
  return make_float4(v.x, v.y, v.z, v.w);
}

// ws layout (floats) — every slot written before read, NO init required:
// [0..1023]     per-block gray maxes: batch b, block x -> ws[b*256 + x]
// [1024..1535]  per-main-block S1 partials (512 blocks)
// [1536..2047]  per-main-block S2 partials

__global__ __launch_bounds__(256) void gmax_kernel(
    const float* __restrict__ gray, float* __restrict__ gpart) {
  const int b = blockIdx.y;
  const int i = (blockIdx.x * 256 + threadIdx.x) << 2;
  const float4 g4 = nt_load4(gray + b * HWn + i);
  float lmax = fmaxf(fmaxf(g4.x, g4.y), fmaxf(g4.z, g4.w));
#pragma unroll
  for (int off = 32; off > 0; off >>= 1)
    lmax = fmaxf(lmax, __shfl_down(lmax, off));
  __shared__ float smax[4];
  const int lane = threadIdx.x & 63, wid = threadIdx.x >> 6;
  if (lane == 0) smax[wid] = lmax;
  __syncthreads();
  if (threadIdx.x == 0) {
    gpart[b * 256 + blockIdx.x] =
        fmaxf(fmaxf(smax[0], smax[1]), fmaxf(smax[2], smax[3]));
  }
}

// Block = 512 threads, 4 image rows (2048 px, 4 px/thread).
// fake/gamma/hdr^e staged in LDS: 3 arrays x 8 rows x 512 cols = 48 KB.
// rw weights streamed with a depth-1 register prefetch (proven in r5;
// depth-2 spilled in r6; device-fence fused epilogue cost ~15us in r6/r7;
// padded-LDS + wave rotation neutral in r9 — all reverted).
__global__ __launch_bounds__(512, 4) void main_kernel(
    const float* __restrict__ fake, const float* __restrict__ gamma,
    const float* __restrict__ hdr, const float* __restrict__ rw,
    const float* __restrict__ ff, const float* __restrict__ gpart,
    float* __restrict__ s1part, float* __restrict__ s2part) {
  __shared__ float smem[3][8][512];  // 48 KB
  __shared__ float sh1[8], sh2[8], sh_gm[4];

  const int b = blockIdx.x >> 7;           // 128 blocks per batch
  const int h0 = (blockIdx.x & 127) << 2;  // first of 4 rows
  const float e = 1.0f - ff[b];

  const float* fb = fake + (size_t)b * HWn;
  const float* gb = gamma + (size_t)b * HWn;
  const float* hb = hdr + (size_t)b * HWn;

  const int t = threadIdx.x;
  const int lr = t >> 7;          // local row 0..3
  const int w0 = (t & 127) << 2;  // col base, multiple of 4
  const int h = h0 + lr;
  const float* rwb = rw + (size_t)b * 25 * HWn + (h << 9) + w0;

  // Prefetch row-0 weights BEFORE the staging barrier: these global loads
  // stay in flight across __syncthreads (only the waitcnt lands after).
  float4 wv[5];
#pragma unroll
  for (int d = 0; d < 5; ++d) wv[d] = nt_load4(rwb + (size_t)d * HWn);

  // Batch gray-max: reduce this batch's 256 per-block partials (waves 0-3).
  if (t < 256) {
    float gm = gpart[(b << 8) + t];
#pragma unroll
    for (int off = 32; off > 0; off >>= 1)
      gm = fmaxf(gm, __shfl_down(gm, off));
    if ((t & 63) == 0) sh_gm[t >> 6] = gm;
  }

  // ---- cooperative staging: 3 arrays x 8 rows x 128 float4 = 3072 ----
  float4* smem4 = (float4*)smem;
#pragma unroll
  for (int k = 0; k < 6; ++k) {
    const int i = t + (k << 9);
    const int a = i >> 10;  // array 0..2
    const int rem = i & 1023;
    const int r = rem >> 7;
    const int c4 = rem & 127;
    const int grow = min(max(h0 - 2 + r, 0), Hn - 1);
    const float* src = (a == 0) ? fb : (a == 1) ? gb : hb;
    float4 v = nt_load4(src + (grow << 9) + (c4 << 2));
    if (a == 2) {
      v.x = __powf(v.x, e);
      v.y = __powf(v.y, e);
      v.z = __powf(v.z, e);
      v.w = __powf(v.w, e);
    }
    smem4[i] = v;
  }
  __syncthreads();

  float Sw[4] = {0, 0, 0, 0}, Sf[4] = {0, 0, 0, 0}, Sf2[4] = {0, 0, 0, 0};
  float Sg[4] = {0, 0, 0, 0}, Sg2[4] = {0, 0, 0, 0}, Sh[4] = {0, 0, 0, 0};

  // Buffer covers cols w0-4 .. w0+7; window uses idx 2..9 (cols w0-2..w0+5).
  float cm[12];
#pragma unroll
  for (int i = 2; i < 10; ++i)
    cm[i] = ((unsigned)(w0 - 4 + i) < (unsigned)Wn) ? 1.0f : 0.0f;
  const int c0 = max(w0 - 4, 0);       // chunk idx 0..3
  const int c2 = min(w0 + 4, Wn - 4);  // chunk idx 8..11 (garbage masked)

#pragma unroll
  for (int dyi = 0; dyi < 5; ++dyi) {
    const int r = lr + dyi;  // staged row 0..7
    const float rmask = ((unsigned)(h + dyi - 2) < (unsigned)Hn) ? 1.0f : 0.0f;

    // current row's weights; immediately start next row's loads
    float4 wc[5];
#pragma unroll
    for (int d = 0; d < 5; ++d) wc[d] = wv[d];
    if (dyi < 4) {
#pragma unroll
      for (int d = 0; d < 5; ++d)
        wv[d] = nt_load4(rwb + (size_t)((dyi + 1) * 5 + d) * HWn);
    }

    const float4 f0 = *(const float4*)&smem[0][r][c0];
    const float4 f1 = *(const float4*)&smem[0][r][w0];
    const float4 f2 = *(const float4*)&smem[0][r][c2];
    const float4 g0 = *(const float4*)&smem[1][r][c0];
    const float4 g1 = *(const float4*)&smem[1][r][w0];
    const float4 g2 = *(const float4*)&smem[1][r][c2];
    const float4 p0 = *(const float4*)&smem[2][r][c0];
    const float4 p1 = *(const float4*)&smem[2][r][w0];
    const float4 p2 = *(const float4*)&smem[2][r][c2];

    float xf[12] = {f0.x, f0.y, f0.z, f0.w, f1.x, f1.y, f1.z, f1.w,
                    f2.x, f2.y, f2.z, f2.w};
    float xg[12] = {g0.x, g0.y, g0.z, g0.w, g1.x, g1.y, g1.z, g1.w,
                    g2.x, g2.y, g2.z, g2.w};
    float xh[12] = {p0.x, p0.y, p0.z, p0.w, p1.x, p1.y, p1.z, p1.w,
                    p2.x, p2.y, p2.z, p2.w};
#pragma unroll
    for (int i2 = 2; i2 < 10; ++i2) {
      const float m = rmask * cm[i2];
      xf[i2] *= m;
      xg[i2] *= m;
      xh[i2] *= m;
    }
#pragma unroll
    for (int dxi = 0; dxi < 5; ++dxi) {
      const float wk[4] = {wc[dxi].x, wc[dxi].y, wc[dxi].z, wc[dxi].w};
#pragma unroll
      for (int j = 0; j < 4; ++j) {
        const float w = wk[j];
        const float f = xf[j + dxi + 2], g = xg[j + dxi + 2],
                    hp = xh[j + dxi + 2];
        Sw[j] += w;
        const float wf = w * f;
        Sf[j] += wf;
        Sf2[j] = fmaf(wf, f, Sf2[j]);
        const float wg = w * g;
        Sg[j] += wg;
        Sg2[j] = fmaf(wg, g, Sg2[j]);
        Sh[j] = fmaf(w, hp, Sh[j]);
      }
    }
  }

  const float ffb = ff[b];
  const float gmax =
      fmaxf(fmaxf(sh_gm[0], sh_gm[1]), fmaxf(sh_gm[2], sh_gm[3]));
  float s1 = 0.0f, s2 = 0.0f;
#pragma unroll
  for (int j = 0; j < 4; ++j) {
    const float invSw = 1.0f / Sw[j];
    const float muf = Sf[j] * invSw;
    const float varf = fmaxf(Sf2[j] * invSw - muf * muf, 0.0f);
    const float stdf = sqrtf(varf + kEps);
    const float mug = Sg[j] * invSw;
    const float varg = fmaxf(Sg2[j] * invSw - mug * mug, 0.0f);
    const float stdg = sqrtf(varg + kEps);
    const float hpmu = Sh[j] * invSw;
    const float stdobj = (1.0f / ffb) * stdg * (hpmu + kEps) * gmax;
    const float r = 1.0f - stdf / (stdf + stdobj);
    const float wblf = Sw[j] - 1.0f;
    s1 = fmaf(r, wblf, s1);
    s2 += wblf;
  }
#pragma unroll
  for (int off = 32; off > 0; off >>= 1) {
    s1 += __shfl_down(s1, off);
    s2 += __shfl_down(s2, off);
  }
  const int lane = t & 63, wid = t >> 6;
  if (lane == 0) {
    sh1[wid] = s1;
    sh2[wid] = s2;
  }
  __syncthreads();
  if (t == 0) {
    float a1 = 0.0f, a2 = 0.0f;
#pragma unroll
    for (int i = 0; i < 8; ++i) {
      a1 += sh1[i];
      a2 += sh2[i];
    }
    s1part[blockIdx.x] = a1;
    s2part[blockIdx.x] = a2;
  }
}

__global__ __launch_bounds__(512) void final_kernel(
    const float* __restrict__ s1part, const float* __restrict__ s2part,
    float* __restrict__ out) {
  const int t = threadIdx.x;
  float s1 = s1part[t];
  float s2 = s2part[t];
#pragma unroll
  for (int off = 32; off > 0; off >>= 1) {
    s1 += __shfl_down(s1, off);
    s2 += __shfl_down(s2, off);
  }
  __shared__ float sh1[8], sh2[8];
  const int lane = t & 63, wid = t >> 6;
  if (lane == 0) {
    sh1[wid] = s1;
    sh2[wid] = s2;
  }
  __syncthreads();
  if (t == 0) {
    float a1 = 0.0f, a2 = 0.0f;
#pragma unroll
    for (int i = 0; i < 8; ++i) {
      a1 += sh1[i];
      a2 += sh2[i];
    }
    out[0] = a1 / a2;
  }
}

extern "C" void kernel_launch(void* const* d_in, const int* in_sizes, int n_in,
                              void* d_out, int out_size, void* d_ws,
                              size_t ws_size, hipStream_t stream) {
  const float* fake = (const float*)d_in[0];
  const float* gamma = (const float*)d_in[1];
  const float* hdr = (const float*)d_in[2];
  const float* rw = (const float*)d_in[3];
  const float* ff = (const float*)d_in[4];
  const float* gray = (const float*)d_in[5];
  float* out = (float*)d_out;
  float* ws = (float*)d_ws;
  float* gpart = ws;          // 1024 slots
  float* s1part = ws + 1024;  // 512 slots
  float* s2part = ws + 1536;  // 512 slots

  gmax_kernel<<<dim3(256, Bn), 256, 0, stream>>>(gray, gpart);
  main_kernel<<<Bn * Hn / 4, 512, 0, stream>>>(fake, gamma, hdr, rw, ff, gpart,
                                               s1part, s2part);
  final_kernel<<<1, 512, 0, stream>>>(s1part, s2part, out);
}